// Round 2
// baseline (531.277 us; speedup 1.0000x reference)
//
#include <hip/hip_runtime.h>
#include <math.h>

#define W 1024
#define H 1024
#define NB 4

// ---------------- kernel 1: per-row inclusive prefix sums (fp64) ----------------
__global__ __launch_bounds__(256) void prefix_rows_k(const float* __restrict__ in,
                                                     double* __restrict__ pre) {
  const int row = blockIdx.x;  // 0 .. NB*H-1
  const float4* r4 = (const float4*)(in + (size_t)row * W);
  double* orow = pre + (size_t)row * W;
  const int t = threadIdx.x;  // each thread: 4 consecutive elements
  float4 v = r4[t];
  double s0 = (double)v.x;
  double s1 = s0 + (double)v.y;
  double s2 = s1 + (double)v.z;
  double s3 = s2 + (double)v.w;
  __shared__ double tot[256];
  tot[t] = s3;
  __syncthreads();
  double acc = s3;
  for (int off = 1; off < 256; off <<= 1) {
    double add = (t >= off) ? tot[t - off] : 0.0;
    __syncthreads();
    acc += add;
    tot[t] = acc;
    __syncthreads();
  }
  double base = acc - s3;  // exclusive prefix of this thread's chunk
  double2* o2 = (double2*)(orow + 4 * t);
  o2[0] = make_double2(base + s0, base + s1);
  o2[1] = make_double2(base + s2, base + s3);
}

// integer half-width of disk row: largest w with w*w <= r2mdy2
__device__ __forceinline__ int iwidth(int r2mdy2) {
  int wv = (int)sqrtf((float)r2mdy2);
  while ((wv + 1) * (wv + 1) <= r2mdy2) ++wv;
  while (wv * wv > r2mdy2) --wv;
  return wv;
}

// ---------------- kernel 2: disk sums + sobel-derived channels ----------------
// block = 256 threads mapped to a 64x4 tile for vertical prefix reuse
__global__ __launch_bounds__(256) void lsp_main_k(const float* __restrict__ dtm,
                                                  const double* __restrict__ pre,
                                                  float* __restrict__ out,
                                                  float* __restrict__ me) {
  __shared__ int w50[101];
  __shared__ int w11[23];
  __shared__ int w5[11];
  __shared__ float areas[2];  // [0]=HS area (r=50), [1]=SM area (r=11)
  const int t = threadIdx.x;
  if (t < 101) {
    int dy = t - 50;
    w50[t] = iwidth(2500 - dy * dy);
  }
  if (t >= 128 && t < 151) {
    int dy = (t - 128) - 11;
    w11[t - 128] = iwidth(121 - dy * dy);
  }
  if (t >= 160 && t < 171) {
    int dy = (t - 160) - 5;
    w5[t - 160] = iwidth(25 - dy * dy);
  }
  __syncthreads();
  if (t == 0) {
    int a = 0;
    for (int i = 0; i < 101; ++i) a += 2 * w50[i] + 1;
    areas[0] = (float)a;   // 7845
  }
  if (t == 64) {
    int a = 0;
    for (int i = 0; i < 23; ++i) a += 2 * w11[i] + 1;
    areas[1] = (float)a;   // 377
  }
  __syncthreads();

  const int x = ((blockIdx.x & 15) << 6) + (t & 63);
  const int y = (((blockIdx.x >> 4) & 255) << 2) + (t >> 6);
  const int b = blockIdx.x >> 12;

  const double* Pb = pre + (size_t)b * H * W;
  const float* Db = dtm + (size_t)b * H * W;

  // row range sum [x-wv, x+wv] with zero padding in x (fp64)
  auto rsum = [&](int yy, int wv) -> double {
    const double* Pr = Pb + (size_t)yy * W;
    int hi = x + wv;
    if (hi > W - 1) hi = W - 1;
    int lo = x - wv - 1;
    double s = Pr[hi];
    if (lo >= 0) s -= Pr[lo];
    return s;
  };

  // ---- tpiHS: disk r=50 ----
  double sHS = 0.0;
  {
    int d0 = (y >= 50) ? -50 : -y;
    int d1 = (y <= H - 1 - 50) ? 50 : (H - 1 - y);
    for (int dy = d0; dy <= d1; ++dy) sHS += rsum(y + dy, w50[dy + 50]);
  }
  // ---- mean_elev: disk r=11 ----
  double s11 = 0.0;
  {
    int d0 = (y >= 11) ? -11 : -y;
    int d1 = (y <= H - 1 - 11) ? 11 : (H - 1 - y);
    for (int dy = d0; dy <= d1; ++dy) s11 += rsum(y + dy, w11[dy + 11]);
  }
  // ---- annulus: disk r=5 minus 3x3 box ----
  double s5 = 0.0;
  {
    int d0 = (y >= 5) ? -5 : -y;
    int d1 = (y <= H - 1 - 5) ? 5 : (H - 1 - y);
    for (int dy = d0; dy <= d1; ++dy) s5 += rsum(y + dy, w5[dy + 5]);
  }
  double s3box = 0.0;
  {
    int d0 = (y >= 1) ? -1 : 0;
    int d1 = (y <= H - 2) ? 1 : 0;
    for (int dy = d0; dy <= d1; ++dy) s3box += rsum(y + dy, 1);
  }
  double annSum = s5 - s3box;

  const float c = Db[(size_t)y * W + x];

  float mHS = (float)(sHS / (double)areas[0]);
  float tpiHS = fminf(fmaxf(c - mHS, -10.f), 10.f);
  tpiHS = (tpiHS + 10.f) * 0.05f;

  float mL = (float)(annSum / 72.0);
  float tpiL = fminf(fmaxf(c - mL, -10.f), 10.f);
  tpiL = (tpiL + 10.f) * 0.05f;

  float meV = (float)(s11 / (double)areas[1]);
  me[((size_t)b * H + y) * W + x] = meV;

  // ---- Sobel / slope / hillshade ----
  auto dv = [&](int yy, int xx) -> float {
    if (yy < 0 || yy >= H || xx < 0 || xx >= W) return 0.f;
    return Db[(size_t)yy * W + xx];
  };
  float v00 = dv(y - 1, x - 1), v01 = dv(y - 1, x), v02 = dv(y - 1, x + 1);
  float v10 = dv(y, x - 1), v12 = dv(y, x + 1);
  float v20 = dv(y + 1, x - 1), v21 = dv(y + 1, x), v22 = dv(y + 1, x + 1);
  float gx = ((v02 - v00) + 2.f * (v12 - v10) + (v22 - v20)) * 0.125f;
  float gy = ((v20 - v00) + 2.f * (v21 - v01) + (v22 - v02)) * 0.125f;
  float g2 = gx * gx + gy * gy;
  float slpR = atanf(sqrtf(g2));
  float slp = sqrtf(slpR * 57.2958f) * 0.1f;
  slp = fminf(slp, 1.0f);
  // cos_sum over the 4 azimuths is identically 0 (angles are pi/2,pi,3pi/2,2pi),
  // so hillshade = clip(cosA*cos(slpR)*255, 0, 255)/255; base>=0 so only /255.
  float base = 0.70710678118654752f * cosf(slpR);
  float hs = fminf(fmaxf(base * 255.f, 0.f), 255.f) * (1.f / 255.f);

  const size_t ch = (size_t)H * W;
  const size_t pix = (size_t)y * W + x;
  float* ob = out + (size_t)b * 6 * ch;
  ob[0 * ch + pix] = tpiHS;
  ob[1 * ch + pix] = slp;
  ob[2 * ch + pix] = tpiL;
  ob[3 * ch + pix] = hs;
}

// ---------------- kernel 3: curvature on smoothed elevation ----------------
__global__ __launch_bounds__(256) void curv_k(const float* __restrict__ me,
                                              float* __restrict__ out) {
  const int gid = blockIdx.x * 256 + threadIdx.x;
  const int x = gid & (W - 1);
  const int y = (gid >> 10) & (H - 1);
  const int b = gid >> 20;
  const float* Mb = me + (size_t)b * H * W;
  auto mv = [&](int yy, int xx) -> float {
    if (yy < 0 || yy >= H || xx < 0 || xx >= W) return 0.f;
    return Mb[(size_t)yy * W + xx];
  };
  float m00 = mv(y - 1, x - 1), m01 = mv(y - 1, x), m02 = mv(y - 1, x + 1);
  float m10 = mv(y, x - 1), m11 = mv(y, x), m12 = mv(y, x + 1);
  float m20 = mv(y + 1, x - 1), m21 = mv(y + 1, x), m22 = mv(y + 1, x + 1);

  float p = ((m02 - m00) + 2.f * (m12 - m10) + (m22 - m20)) * 0.125f;
  float q = ((m20 - m00) + 2.f * (m21 - m01) + (m22 - m02)) * 0.125f;
  float r = ((m00 - 2.f * m01 + m02) + (m10 - 2.f * m11 + m12) +
             (m20 - 2.f * m21 + m22)) * (1.f / 3.f);
  float tt = ((m00 + m01 + m02) - 2.f * (m10 + m11 + m12) +
              (m20 + m21 + m22)) * (1.f / 3.f);
  float s = (m00 - m02 - m20 + m22) * 0.25f;

  float g = p * p + q * q;
  float denom = g * sqrtf(g) + 1e-12f;
  float crvPln = (q * q * r - 2.f * p * q * s + p * p * tt) / denom;
  float crvPro = (p * p * r + 2.f * p * q * s + q * p * tt) / denom;  // q*p*t as in source
  crvPln = (fminf(fmaxf(crvPln, -0.1f), 0.1f) + 0.1f) * 5.f;
  crvPro = (fminf(fmaxf(crvPro, -0.1f), 0.1f) + 0.1f) * 5.f;

  const size_t ch = (size_t)H * W;
  const size_t pix = (size_t)y * W + x;
  float* ob = out + (size_t)b * 6 * ch;
  ob[4 * ch + pix] = crvPro;
  ob[5 * ch + pix] = crvPln;
}

extern "C" void kernel_launch(void* const* d_in, const int* in_sizes, int n_in,
                              void* d_out, int out_size, void* d_ws, size_t ws_size,
                              hipStream_t stream) {
  const float* dtm = (const float*)d_in[0];
  float* out = (float*)d_out;
  double* pre = (double*)d_ws;                       // NB*H*W doubles (32 MB)
  float* me = (float*)(pre + (size_t)NB * H * W);    // NB*H*W floats (16 MB)

  prefix_rows_k<<<NB * H, 256, 0, stream>>>(dtm, pre);
  const int tile_blocks = NB * (H / 4) * (W / 64);   // 16384
  lsp_main_k<<<tile_blocks, 256, 0, stream>>>(dtm, pre, out, me);
  const int npix_blocks = NB * H * W / 256;          // 16384
  curv_k<<<npix_blocks, 256, 0, stream>>>(me, out);
}